// Round 17
// baseline (114.730 us; speedup 1.0000x reference)
//
#include <hip/hip_runtime.h>

// ---------------------------------------------------------------------------
// MultiHeadAttentionWindow: B=8 K=4000 D=256 H=8 DQ=DV=32 WIN=200 PAD=50 STEP=100
// Pipeline (6 launches): prep_weights; gemm5<0>(q) gemm5<1>(k) gemm5<2>(v);
//   attn_win; gemm5<3>(out).  [separate launches -> per-mode attribution]
// Round-17: occupancy + attribution.
//   - A in REGISTERS (wave-tile 16x128: areg = 8 x bf16x8 = 32 VGPR, acc = 32)
//     -> LDS = B-dbuf only (32KB), VGPR ~110 -> 16 waves/CU (2x r16's 8).
//     All slow variants r7-r16 had 50-131KB LDS -> 2 blocks/CU lockstep.
//   - proj split per-mode: profiler finally names mode costs.
//   - epilogues = r14 direct writes (write-coalescing proven null in r16).
// ---------------------------------------------------------------------------

typedef __bf16 bf16_t;
typedef __bf16 bf16x8 __attribute__((ext_vector_type(8)));
typedef float  f32x4  __attribute__((ext_vector_type(4)));

#define MFMA16(a, b, c) __builtin_amdgcn_mfma_f32_16x16x32_bf16((a), (b), (c), 0, 0, 0)

typedef __attribute__((address_space(1))) const unsigned char gas_u8;
typedef __attribute__((address_space(3))) unsigned char las_u8;

static __device__ __forceinline__ void gload16(const void* g, void* l) {
  __builtin_amdgcn_global_load_lds((gas_u8*)g, (las_u8*)l, 16, 0, 0);
}

static __device__ __forceinline__ bf16x8 cvt8(float4 a, float4 b) {
  bf16x8 r;
  r[0] = (bf16_t)a.x; r[1] = (bf16_t)a.y; r[2] = (bf16_t)a.z; r[3] = (bf16_t)a.w;
  r[4] = (bf16_t)b.x; r[5] = (bf16_t)b.y; r[6] = (bf16_t)b.z; r[7] = (bf16_t)b.w;
  return r;
}

static __device__ __forceinline__ unsigned short bbits(bf16_t v) {
  union { bf16_t b; unsigned short u; } c; c.b = v; return c.u;
}

// ---- weight transpose + bf16 convert: Wt[n][k] = bf16(W[k][n]), 4 matrices ----
__global__ __launch_bounds__(256)
void prep_weights(const float* __restrict__ Wq, const float* __restrict__ Wk,
                  const float* __restrict__ Wv, const float* __restrict__ Wo,
                  bf16_t* __restrict__ wt) {
  const int mat  = blockIdx.x >> 6;
  const int tile = blockIdx.x & 63;
  const int kt = (tile >> 3) * 32, nt = (tile & 7) * 32;
  const float* W = (mat == 0) ? Wq : (mat == 1) ? Wk : (mat == 2) ? Wv : Wo;
  __shared__ float t[32][33];
  const int tx = threadIdx.x & 31, ty = threadIdx.x >> 5;  // ty 0..7
#pragma unroll
  for (int i = 0; i < 32; i += 8)
    t[ty + i][tx] = W[(size_t)(kt + ty + i) * 256 + nt + tx];
  __syncthreads();
  bf16_t* dst = wt + (size_t)mat * 65536;
#pragma unroll
  for (int i = 0; i < 32; i += 8)
    dst[(size_t)(nt + ty + i) * 256 + kt + tx] = (bf16_t)t[tx][ty + i];
}

// ---- GEMM: [M x 256] x [256 x 256] + bias; block 64m x 256n, 8 waves ----
// wave w: rows (w&3)*16, cols (w>>2)*128. A in regs (8 x bf16x8), B dbuf LDS.
// MODE 0: fp32 in -> bf16 qb row-major (*oscale)
// MODE 1: fp32 in -> bf16 kb rows b*4064+t+50 (+left-pad replicate)
// MODE 2: fp32 in -> bf16 vt[(b*256+n)][t+50] scatter (+left-pad replicate)
// MODE 3: bf16 in (ao) -> fp32 out row-major
template <int MODE>
__global__ __launch_bounds__(512)
void gemm5(const void* __restrict__ Xv, const bf16_t* __restrict__ W,
           const float* __restrict__ bias, void* __restrict__ Out, int M,
           float oscale) {
  constexpr bool INB = (MODE == 3);
  __shared__ __align__(16) char ldsB[2 * 16384];   // B dbuf only

  const int tid  = threadIdx.x;
  const int lane = tid & 63;
  const int w    = tid >> 6;            // 0..7
  const int wm   = (w & 3) * 16;        // wave row offset
  const int wn   = (w >> 2) * 128;      // wave col offset
  const int lo   = lane & 15, hi = lane >> 4;
  const int m0   = blockIdx.x * 64;

  // ---- A fragments into registers (row = wave row + lo, once) ----
  int ar = m0 + wm + lo; if (ar >= M) ar = M - 1;
  bf16x8 areg[8];
  if constexpr (!INB) {
    const float4* ap = (const float4*)((const float*)Xv + (size_t)ar * 256);
#pragma unroll
    for (int t = 0; t < 8; ++t)
      areg[t] = cvt8(ap[t * 8 + hi * 2], ap[t * 8 + hi * 2 + 1]);
  } else {
    const bf16_t* ap = (const bf16_t*)Xv + (size_t)ar * 256;
#pragma unroll
    for (int t = 0; t < 8; ++t)
      areg[t] = *(const bf16x8*)(ap + t * 32 + hi * 8);
  }

  // ---- B staging: 2 gloads/thread/tile; slot s -> row s>>2, chunk s&3 ----
  const bf16_t* bsrc[2];
  int boff[2];
#pragma unroll
  for (int j = 0; j < 2; ++j) {
    const int s = j * 512 + tid;
    bsrc[j] = W + (size_t)(s >> 2) * 256 + ((s & 3) << 3);
    boff[j] = s * 16;
  }
  int bbase[8];
#pragma unroll
  for (int ni = 0; ni < 8; ++ni)
    bbase[ni] = (wn + ni * 16 + lo) * 64 + hi * 16;

  // prologue: issue B tile 0
#pragma unroll
  for (int j = 0; j < 2; ++j) gload16(bsrc[j], ldsB + boff[j]);

  f32x4 acc[8] = {};

  for (int t = 0; t < 8; ++t) {
    const int cur = (t & 1) * 16384;
    if (t < 7) {
      const int nxt = ((t + 1) & 1) * 16384;
#pragma unroll
      for (int j = 0; j < 2; ++j) gload16(bsrc[j] + (t + 1) * 32, ldsB + nxt + boff[j]);
      asm volatile("s_waitcnt vmcnt(2)" ::: "memory");   // tile t landed
    } else {
      asm volatile("s_waitcnt vmcnt(0)" ::: "memory");
    }
    __builtin_amdgcn_sched_barrier(0);
    __builtin_amdgcn_s_barrier();

#pragma unroll
    for (int ni = 0; ni < 8; ++ni) {
      const bf16x8 bfv = *(const bf16x8*)(ldsB + cur + bbase[ni]);
      acc[ni] = MFMA16(areg[t], bfv, acc[ni]);
    }
    __builtin_amdgcn_sched_barrier(0);
    __builtin_amdgcn_s_barrier();       // buf[cur] free for re-stage
  }

  // ---- epilogue: C/D layout col = lane&15, row = (lane>>4)*4 + r ----
  const int mb = m0 + wm + hi * 4;      // 4-aligned; 4000%4==0 -> same batch
  if (mb >= M) return;
#pragma unroll
  for (int ni = 0; ni < 8; ++ni) {
    const int n = wn + ni * 16 + lo;
    const float bia = bias[n];
    if constexpr (MODE == 0) {
      bf16_t* O = (bf16_t*)Out;
#pragma unroll
      for (int rr = 0; rr < 4; ++rr)
        O[(size_t)(mb + rr) * 256 + n] = (bf16_t)((acc[ni][rr] + bia) * oscale);
    } else if constexpr (MODE == 1) {
      const int b = mb / 4000, t = mb - b * 4000;
      bf16_t* O = (bf16_t*)Out;
#pragma unroll
      for (int rr = 0; rr < 4; ++rr) {
        const bf16_t v = (bf16_t)(acc[ni][rr] + bia);
        O[((size_t)b * 4064 + t + 50 + rr) * 256 + n] = v;
        if (t == 0 && rr == 0)
          for (int p = 0; p < 50; ++p)
            O[((size_t)b * 4064 + p) * 256 + n] = v;
      }
    } else if constexpr (MODE == 2) {
      const int b = mb / 4000, t = mb - b * 4000;
      const size_t vrow = ((size_t)(b * 256 + n)) * 4064;
      bf16_t* O = (bf16_t*)Out;
      unsigned short e0 = bbits((bf16_t)(acc[ni][0] + bia));
      unsigned short e1 = bbits((bf16_t)(acc[ni][1] + bia));
      unsigned short e2 = bbits((bf16_t)(acc[ni][2] + bia));
      unsigned short e3 = bbits((bf16_t)(acc[ni][3] + bia));
      unsigned* O32 = (unsigned*)(O + vrow + t + 50);  // (t+50) even -> aligned
      O32[0] = (unsigned)e0 | ((unsigned)e1 << 16);
      O32[1] = (unsigned)e2 | ((unsigned)e3 << 16);
      if (t == 0) {                     // replicate left pad p<50
        const unsigned vv = (unsigned)e0 | ((unsigned)e0 << 16);
        unsigned* P = (unsigned*)(O + vrow);
#pragma unroll
        for (int p = 0; p < 25; ++p) P[p] = vv;
      }
    } else {
      float* O = (float*)Out;
#pragma unroll
      for (int rr = 0; rr < 4; ++rr)
        O[(size_t)(mb + rr) * 256 + n] = acc[ni][rr] + bia;
    }
  }
}

// ---- windowed attention: one block per (b',h,window), 7 waves = 7 row-strips ----
// Chunked: per 32-col chunk {2x QK MFMA -> exp -> 16x32 LDS bounce -> PV 3 MFMA}.
// No cross-lane ops, no barriers; denom via E@ones; normalize after PV.
// vt rows: (b*256 + h*32 + dv); unwritten tails are causally masked (E==0).
__global__ __launch_bounds__(448)
void attn_win(const bf16_t* __restrict__ qb, const bf16_t* __restrict__ kb,
              const bf16_t* __restrict__ vt, bf16_t* __restrict__ ao) {
  const int blk = blockIdx.x;
  const int n = blk % 40;
  const int h = (blk / 40) & 7;
  const int b = blk / 320;
  const int wv = threadIdx.x >> 6;     // strip 0..6, rows i in [50+16wv, 66+16wv)
  const int lane = threadIdx.x & 63;
  const int lo = lane & 15, hi = lane >> 4;

  __shared__ __align__(16) bf16_t E[7][16][40];  // per-wave 16x32 chunk (pad 40)

  const int i0 = 50 + 16 * wv;
  int jtmax = (65 + 16 * wv) >> 4;     // last 16-tile with any unmasked element
  if (jtmax > 9) jtmax = 9;
  const int reach = jtmax * 16 + 16;

  // Q fragment (pre-scaled by 1/sqrt(200)): row lo -> token t = n*100+16wv+lo
  int tq = n * 100 + 16 * wv + lo;
  if (tq > 3999) tq = 3999;            // rows i>=150 are discarded at store
  const bf16x8 qf = *(const bf16x8*)&qb[((size_t)b * 4000 + tq) * 256 + h * 32 + hi * 8];

  const f32x4 zero = {0.f, 0.f, 0.f, 0.f};
  bf16x8 onesf;
#pragma unroll
  for (int u = 0; u < 8; ++u) onesf[u] = (bf16_t)1.0f;

  f32x4 o0 = zero, o1 = zero, sm = zero;
  const size_t vbase = ((size_t)(b * 256 + h * 32)) * 4064 + n * 100;
  const size_t kbase = ((size_t)(b * 4064 + n * 100)) * 256 + h * 32 + hi * 8;
  const int dbase = i0 + hi * 4 - lo;  // d = dbase + r - 16*jt

#pragma unroll
  for (int kt = 0; kt < 5; ++kt) if (kt * 32 < reach) {
    // two score tiles -> E chunk [16][32]
#pragma unroll
    for (int half = 0; half < 2; ++half) {
      const int jt = kt * 2 + half;
      if (jt <= jtmax) {
        const bf16x8 kf = *(const bf16x8*)&kb[kbase + (size_t)(jt * 16 + lo) * 256];
        const f32x4 s = MFMA16(qf, kf, zero);
#pragma unroll
        for (int r = 0; r < 4; ++r) {
          const int d = dbase + r - jt * 16;
          const float df = (float)d;
          float c = __builtin_amdgcn_rcpf(__builtin_fmaf(0.25f * df, df, 1.f));
          c = (d == 0) ? 0.f : c;      // eye-mask: diagonal score -> 0 -> e=1
          float e = __expf(s[r] * c);
          e = (d < 0) ? 0.f : e;       // causal mask (also kills garbage-K j's)
          E[wv][hi * 4 + r][half * 16 + lo] = (bf16_t)e;
        }
      } else {
#pragma unroll
        for (int r = 0; r < 4; ++r)
          E[wv][hi * 4 + r][half * 16 + lo] = (bf16_t)0.f;
      }
    }
    // PV + denom for this 32-col chunk (wave-private LDS, in-order DS)
    const bf16x8 pf = *(const bf16x8*)&E[wv][lo][hi * 8];
    const bf16x8 v0 = *(const bf16x8*)&vt[vbase + (size_t)lo * 4064 + kt * 32 + hi * 8];
    const bf16x8 v1 = *(const bf16x8*)&vt[vbase + (size_t)(16 + lo) * 4064 + kt * 32 + hi * 8];
    o0 = MFMA16(pf, v0, o0);
    o1 = MFMA16(pf, v1, o1);
    sm = MFMA16(pf, onesf, sm);
  }

  // store central rows (i in [50,150)): out = o * rcp(rowsum); rowsum >= 1
#pragma unroll
  for (int r = 0; r < 4; ++r) {
    const int i = i0 + hi * 4 + r;
    if (i < 150) {
      const float ri = __builtin_amdgcn_rcpf(sm[r]);
      const int t = n * 100 + i - 50;
      bf16_t* op = &ao[((size_t)b * 4000 + t) * 256 + h * 32];
      op[lo]      = (bf16_t)(o0[r] * ri);
      op[16 + lo] = (bf16_t)(o1[r] * ri);
    }
  }
}

// ---------------------------------------------------------------------------
extern "C" void kernel_launch(void* const* d_in, const int* in_sizes, int n_in,
                              void* d_out, int out_size, void* d_ws, size_t ws_size,
                              hipStream_t stream) {
  (void)in_sizes; (void)n_in; (void)out_size;
  const float* query = (const float*)d_in[0];
  const float* key   = (const float*)d_in[1];
  const float* value = (const float*)d_in[2];
  const float* Wq = (const float*)d_in[3];
  const float* bq = (const float*)d_in[4];
  const float* Wk = (const float*)d_in[5];
  const float* bk = (const float*)d_in[6];
  const float* Wv = (const float*)d_in[7];
  const float* bv = (const float*)d_in[8];
  const float* Wo = (const float*)d_in[9];
  const float* bo = (const float*)d_in[10];

  // batch chunk (ws is large enough for bc=8 in practice)
  int bc = 8;
  while (bc > 1 && 524288ull + (unsigned long long)bc * 8257536ull > (unsigned long long)ws_size)
    bc >>= 1;

  bf16_t* wt = (bf16_t*)d_ws;                           // 4 * 65536
  bf16_t* qb = wt + 4 * 65536;                          // bc*4000*256
  bf16_t* kb = qb + (size_t)bc * 4000 * 256;            // bc*4064*256
  bf16_t* vt = kb + (size_t)bc * 4064 * 256;            // bc*256*4064
  bf16_t* ao = vt + (size_t)bc * 256 * 4064;            // bc*4000*256

  prep_weights<<<256, 256, 0, stream>>>(Wq, Wk, Wv, Wo, wt);

  const float qscale = 0.07071067811865475f;  // 1/sqrt(200) folded into qb

  for (int b0 = 0; b0 < 8; b0 += bc) {
    const int M = bc * 4000;
    const int mblk = (M + 63) / 64;
    const float* qx = query + (size_t)b0 * 4000 * 256;
    const float* kx = key   + (size_t)b0 * 4000 * 256;
    const float* vx = value + (size_t)b0 * 4000 * 256;
    float* ox = (float*)d_out + (size_t)b0 * 4000 * 256;

    gemm5<0><<<mblk, 512, 0, stream>>>(qx, wt + 0 * 65536, bq, qb, M, qscale);
    gemm5<1><<<mblk, 512, 0, stream>>>(kx, wt + 1 * 65536, bk, kb, M, 1.f);
    gemm5<2><<<mblk, 512, 0, stream>>>(vx, wt + 2 * 65536, bv, vt, M, 1.f);
    attn_win<<<bc * 320, 448, 0, stream>>>(qb, kb, vt, ao);
    gemm5<3><<<mblk, 512, 0, stream>>>(ao, wt + 3 * 65536, bo, ox, M, 1.f);
  }
}

// Round 19
// 110.348 us; speedup vs baseline: 1.0397x; 1.0397x over previous
//
#include <hip/hip_runtime.h>

// ---------------------------------------------------------------------------
// MultiHeadAttentionWindow: B=8 K=4000 D=256 H=8 DQ=DV=32 WIN=200 PAD=50 STEP=100
// Pipeline (7 launches): prep_weights; gemmR(q) gemmR(k) gemmR(v) [row-major
//   outputs, identical bodies]; vtrans (vb -> vt transpose + pad); attn_win
//   (k read with clamp = replicate pad); gemmR(out).
// Round-19: r18 + ONE fix — vtrans store was unguarded past t=3999 (grid
//   covers 4032 rows), overflowing each 4064-col vt row by up to 32 elems
//   into the NEXT row's left-pad region -> absmax 0.165. Store now guarded
//   per-4B (t-pairs never straddle 4000 since both are even).
// ---------------------------------------------------------------------------

typedef __bf16 bf16_t;
typedef __bf16 bf16x8 __attribute__((ext_vector_type(8)));
typedef float  f32x4  __attribute__((ext_vector_type(4)));

#define MFMA16(a, b, c) __builtin_amdgcn_mfma_f32_16x16x32_bf16((a), (b), (c), 0, 0, 0)

typedef __attribute__((address_space(1))) const unsigned char gas_u8;
typedef __attribute__((address_space(3))) unsigned char las_u8;

static __device__ __forceinline__ void gload16(const void* g, void* l) {
  __builtin_amdgcn_global_load_lds((gas_u8*)g, (las_u8*)l, 16, 0, 0);
}

static __device__ __forceinline__ bf16x8 cvt8(float4 a, float4 b) {
  bf16x8 r;
  r[0] = (bf16_t)a.x; r[1] = (bf16_t)a.y; r[2] = (bf16_t)a.z; r[3] = (bf16_t)a.w;
  r[4] = (bf16_t)b.x; r[5] = (bf16_t)b.y; r[6] = (bf16_t)b.z; r[7] = (bf16_t)b.w;
  return r;
}

static __device__ __forceinline__ unsigned short bbits(bf16_t v) {
  union { bf16_t b; unsigned short u; } c; c.b = v; return c.u;
}

// ---- weight transpose + bf16 convert: Wt[n][k] = bf16(W[k][n]), 4 matrices ----
__global__ __launch_bounds__(256)
void prep_weights(const float* __restrict__ Wq, const float* __restrict__ Wk,
                  const float* __restrict__ Wv, const float* __restrict__ Wo,
                  bf16_t* __restrict__ wt) {
  const int mat  = blockIdx.x >> 6;
  const int tile = blockIdx.x & 63;
  const int kt = (tile >> 3) * 32, nt = (tile & 7) * 32;
  const float* W = (mat == 0) ? Wq : (mat == 1) ? Wk : (mat == 2) ? Wv : Wo;
  __shared__ float t[32][33];
  const int tx = threadIdx.x & 31, ty = threadIdx.x >> 5;  // ty 0..7
#pragma unroll
  for (int i = 0; i < 32; i += 8)
    t[ty + i][tx] = W[(size_t)(kt + ty + i) * 256 + nt + tx];
  __syncthreads();
  bf16_t* dst = wt + (size_t)mat * 65536;
#pragma unroll
  for (int i = 0; i < 32; i += 8)
    dst[(size_t)(nt + ty + i) * 256 + kt + tx] = (bf16_t)t[tx][ty + i];
}

// ---- GEMM: [M x 256] x [256 x 256] + bias -> ROW-MAJOR out. 64m x 256n,
// 4 waves (wave w = cols [w*64,w*64+64)), per-K-tile double-buffered gload.
// INF32: input fp32 (cvt on LDS read, XOR-swizzled slots) else bf16.
// OUTF32: output fp32 else bf16 (*oscale).
template <int INF32, int OUTF32>
__global__ __launch_bounds__(256)
void gemmR(const void* __restrict__ Xv, const bf16_t* __restrict__ W,
           const float* __restrict__ bias, void* __restrict__ Out, int M,
           float oscale) {
  constexpr int ASZ = INF32 ? 8192 : 4096;
  constexpr int STRIDE = ASZ + 16384;
  __shared__ __align__(16) char lds[2 * STRIDE];

  const int tid  = threadIdx.x;
  const int lane = tid & 63;
  const int w    = tid >> 6;           // wave 0..3
  const int lo   = lane & 15, hi = lane >> 4;
  const int m0   = blockIdx.x * 64;

  // ---- A staging sources ----
  const void* asrc[2];
  int aoff[2];
  if constexpr (INF32) {
    // 512 slots x 16B: slot s: row=s>>3, cs=s&7 holds global chunk cs^(row&7)
#pragma unroll
    for (int j = 0; j < 2; ++j) {
      const int s = j * 256 + tid;
      const int row = s >> 3, cs = s & 7;
      int ar = m0 + row; if (ar >= M) ar = M - 1;
      asrc[j] = (const float*)Xv + (size_t)ar * 256 + ((cs ^ (row & 7)) << 2);
      aoff[j] = s * 16;
    }
  } else {
    // 256 slots x 16B: slot s: row=s>>2, cs=s&3 holds global chunk cs^(row&3)
    const int s = tid;
    const int row = s >> 2, cs = s & 3;
    int ar = m0 + row; if (ar >= M) ar = M - 1;
    asrc[0] = (const bf16_t*)Xv + (size_t)ar * 256 + ((cs ^ (row & 3)) << 3);
    aoff[0] = s * 16;
    asrc[1] = asrc[0]; aoff[1] = aoff[0];
  }
  // ---- B staging: 4 gloads; slot s: row=s>>2, ch=s&3 (linear) ----
  const bf16_t* bsrc[4];
  int boff[4];
#pragma unroll
  for (int j = 0; j < 4; ++j) {
    const int s = j * 256 + tid;
    bsrc[j] = W + (size_t)(s >> 2) * 256 + ((s & 3) << 3);
    boff[j] = ASZ + s * 16;
  }
  int bbase[4];
#pragma unroll
  for (int ni = 0; ni < 4; ++ni)
    bbase[ni] = ASZ + (w * 64 + ni * 16 + lo) * 64 + hi * 16;

  // prologue: issue tile 0 into buffer 0
  if constexpr (INF32) {
    gload16(asrc[0], lds + aoff[0]);
    gload16((const float*)asrc[1], lds + aoff[1]);
  } else {
    gload16(asrc[0], lds + aoff[0]);
  }
#pragma unroll
  for (int j = 0; j < 4; ++j) gload16(bsrc[j], lds + boff[j]);

  f32x4 acc[4][4] = {};

  for (int t = 0; t < 8; ++t) {
    const int cur = (t & 1) * STRIDE;
    if (t < 7) {
      const int nxt = ((t + 1) & 1) * STRIDE;
      if constexpr (INF32) {
        gload16((const float*)asrc[0] + (t + 1) * 32, lds + nxt + aoff[0]);
        gload16((const float*)asrc[1] + (t + 1) * 32, lds + nxt + aoff[1]);
      } else {
        gload16((const bf16_t*)asrc[0] + (t + 1) * 32, lds + nxt + aoff[0]);
      }
#pragma unroll
      for (int j = 0; j < 4; ++j)
        gload16(bsrc[j] + (t + 1) * 32, lds + nxt + boff[j]);
      if constexpr (INF32) {
        asm volatile("s_waitcnt vmcnt(6)" ::: "memory");
      } else {
        asm volatile("s_waitcnt vmcnt(5)" ::: "memory");
      }
    } else {
      asm volatile("s_waitcnt vmcnt(0)" ::: "memory");
    }
    __builtin_amdgcn_sched_barrier(0);
    __builtin_amdgcn_s_barrier();

    bf16x8 af[4], bfv[4];
#pragma unroll
    for (int mi = 0; mi < 4; ++mi) {
      const int r = mi * 16 + lo;
      if constexpr (INF32) {
        const int ab = cur + r * 128 + (((2 * hi) ^ (r & 7)) << 4);
        const float4 v0 = *(const float4*)(lds + ab);
        const float4 v1 = *(const float4*)(lds + (ab ^ 16));
        af[mi] = cvt8(v0, v1);
      } else {
        const int ab = cur + r * 64 + ((hi ^ (r & 3)) << 4);
        af[mi] = *(const bf16x8*)(lds + ab);
      }
    }
#pragma unroll
    for (int ni = 0; ni < 4; ++ni)
      bfv[ni] = *(const bf16x8*)(lds + cur + bbase[ni]);
#pragma unroll
    for (int mi = 0; mi < 4; ++mi)
#pragma unroll
      for (int ni = 0; ni < 4; ++ni)
        acc[mi][ni] = MFMA16(af[mi], bfv[ni], acc[mi][ni]);
    __builtin_amdgcn_sched_barrier(0);
    __builtin_amdgcn_s_barrier();
  }

  // epilogue: C/D layout col = lane&15, row = (lane>>4)*4 + r  [m89-verified]
#pragma unroll
  for (int mi = 0; mi < 4; ++mi) {
    const int mb = m0 + mi * 16 + hi * 4;   // 4-aligned; M % 4 == 0
    if (mb >= M) continue;
#pragma unroll
    for (int ni = 0; ni < 4; ++ni) {
      const int n = w * 64 + ni * 16 + lo;
      const float bia = bias[n];
      if constexpr (OUTF32) {
        float* O = (float*)Out;
#pragma unroll
        for (int rr = 0; rr < 4; ++rr)
          O[(size_t)(mb + rr) * 256 + n] = acc[mi][ni][rr] + bia;
      } else {
        bf16_t* O = (bf16_t*)Out;
#pragma unroll
        for (int rr = 0; rr < 4; ++rr)
          O[(size_t)(mb + rr) * 256 + n] = (bf16_t)((acc[mi][ni][rr] + bia) * oscale);
      }
    }
  }
}

// ---- vb [b][4000][256] -> vt [b*256+n][4064] (p = t+50), + left-pad ----
// grid (63, 4, bc); 64t x 64n tile per block; both sides coalesced.
// Store guarded at t<4000 (r19 fix: unguarded store overflowed the 4064-col
// row into the next row's left pad).
__global__ __launch_bounds__(256)
void vtrans(const bf16_t* __restrict__ vb, bf16_t* __restrict__ vt) {
  const int t0 = blockIdx.x * 64, n0 = blockIdx.y * 64, b = blockIdx.z;
  __shared__ bf16_t T[64][72];         // T[n][t]
  const int tid = threadIdx.x;
#pragma unroll
  for (int u = 0; u < 2; ++u) {
    const int s = u * 256 + tid;       // 512 slots: row=s>>3, cc=s&7
    const int row = s >> 3, cc = s & 7;
    int t = t0 + row; if (t > 3999) t = 3999;
    const bf16x8 v = *(const bf16x8*)&vb[((size_t)b * 4000 + t) * 256 + n0 + cc * 8];
#pragma unroll
    for (int e = 0; e < 8; ++e) T[cc * 8 + e][row] = v[e];
  }
  __syncthreads();
#pragma unroll
  for (int u = 0; u < 2; ++u) {
    const int s = u * 256 + tid;
    const int nr = s >> 3, cc = s & 7;
    const int tb = t0 + cc * 8;        // first t covered by this chunk
    bf16_t* dst = vt + ((size_t)b * 256 + n0 + nr) * 4064 + 50 + tb;
    const bf16_t* src = &T[nr][cc * 8];
#pragma unroll
    for (int e = 0; e < 4; ++e)        // each unsigned covers t = tb+2e, tb+2e+1
      if (tb + 2 * e < 4000)
        ((unsigned*)dst)[e] = ((const unsigned*)src)[e];
  }
  if (blockIdx.x == 0 && tid < 64) {   // replicate left pad p<50 := V[0][n]
    const unsigned short e = bbits(T[tid][0]);
    const unsigned vv = (unsigned)e | ((unsigned)e << 16);
    unsigned* P = (unsigned*)(vt + ((size_t)b * 256 + n0 + tid) * 4064);
#pragma unroll
    for (int p = 0; p < 25; ++p) P[p] = vv;
  }
}

// ---- windowed attention: one block per (b',h,window), 7 waves = 7 row-strips ----
// K read ROW-MAJOR with clamp(t) = replicate pad (left edge = K[0]; right-tail
// entries are provably causally masked, E == exact 0). vt rows (b*256+n).
__global__ __launch_bounds__(448)
void attn_win(const bf16_t* __restrict__ qb, const bf16_t* __restrict__ kr,
              const bf16_t* __restrict__ vt, bf16_t* __restrict__ ao) {
  const int blk = blockIdx.x;
  const int n = blk % 40;
  const int h = (blk / 40) & 7;
  const int b = blk / 320;
  const int wv = threadIdx.x >> 6;     // strip 0..6, rows i in [50+16wv, 66+16wv)
  const int lane = threadIdx.x & 63;
  const int lo = lane & 15, hi = lane >> 4;

  __shared__ __align__(16) bf16_t E[7][16][40];  // per-wave 16x32 chunk (pad 40)

  const int i0 = 50 + 16 * wv;
  int jtmax = (65 + 16 * wv) >> 4;     // last 16-tile with any unmasked element
  if (jtmax > 9) jtmax = 9;
  const int reach = jtmax * 16 + 16;

  // Q fragment (pre-scaled by 1/sqrt(200)): row lo -> token t = n*100+16wv+lo
  int tq = n * 100 + 16 * wv + lo;
  if (tq > 3999) tq = 3999;            // rows i>=150 are discarded at store
  const bf16x8 qf = *(const bf16x8*)&qb[((size_t)b * 4000 + tq) * 256 + h * 32 + hi * 8];

  const f32x4 zero = {0.f, 0.f, 0.f, 0.f};
  bf16x8 onesf;
#pragma unroll
  for (int u = 0; u < 8; ++u) onesf[u] = (bf16_t)1.0f;

  f32x4 o0 = zero, o1 = zero, sm = zero;
  const size_t vbase = ((size_t)(b * 256 + h * 32)) * 4064 + n * 100;
  const int dbase = i0 + hi * 4 - lo;  // d = dbase + r - 16*jt

#pragma unroll
  for (int kt = 0; kt < 5; ++kt) if (kt * 32 < reach) {
    // two score tiles -> E chunk [16][32]
#pragma unroll
    for (int half = 0; half < 2; ++half) {
      const int jt = kt * 2 + half;
      if (jt <= jtmax) {
        int tk = n * 100 + jt * 16 + lo - 50;          // clamp = edge pad
        tk = (tk < 0) ? 0 : (tk > 3999 ? 3999 : tk);
        const bf16x8 kf = *(const bf16x8*)&kr[((size_t)b * 4000 + tk) * 256 + h * 32 + hi * 8];
        const f32x4 s = MFMA16(qf, kf, zero);
#pragma unroll
        for (int r = 0; r < 4; ++r) {
          const int d = dbase + r - jt * 16;
          const float df = (float)d;
          float c = __builtin_amdgcn_rcpf(__builtin_fmaf(0.25f * df, df, 1.f));
          c = (d == 0) ? 0.f : c;      // eye-mask: diagonal score -> 0 -> e=1
          float e = __expf(s[r] * c);
          e = (d < 0) ? 0.f : e;       // causal mask
          E[wv][hi * 4 + r][half * 16 + lo] = (bf16_t)e;
        }
      } else {
#pragma unroll
        for (int r = 0; r < 4; ++r)
          E[wv][hi * 4 + r][half * 16 + lo] = (bf16_t)0.f;
      }
    }
    // PV + denom for this 32-col chunk (wave-private LDS, in-order DS)
    const bf16x8 pf = *(const bf16x8*)&E[wv][lo][hi * 8];
    const bf16x8 v0 = *(const bf16x8*)&vt[vbase + (size_t)lo * 4064 + kt * 32 + hi * 8];
    const bf16x8 v1 = *(const bf16x8*)&vt[vbase + (size_t)(16 + lo) * 4064 + kt * 32 + hi * 8];
    o0 = MFMA16(pf, v0, o0);
    o1 = MFMA16(pf, v1, o1);
    sm = MFMA16(pf, onesf, sm);
  }

  // store central rows (i in [50,150)): out = o * rcp(rowsum); rowsum >= 1
#pragma unroll
  for (int r = 0; r < 4; ++r) {
    const int i = i0 + hi * 4 + r;
    if (i < 150) {
      const float ri = __builtin_amdgcn_rcpf(sm[r]);
      const int t = n * 100 + i - 50;
      bf16_t* op = &ao[((size_t)b * 4000 + t) * 256 + h * 32];
      op[lo]      = (bf16_t)(o0[r] * ri);
      op[16 + lo] = (bf16_t)(o1[r] * ri);
    }
  }
}

// ---------------------------------------------------------------------------
extern "C" void kernel_launch(void* const* d_in, const int* in_sizes, int n_in,
                              void* d_out, int out_size, void* d_ws, size_t ws_size,
                              hipStream_t stream) {
  (void)in_sizes; (void)n_in; (void)out_size;
  const float* query = (const float*)d_in[0];
  const float* key   = (const float*)d_in[1];
  const float* value = (const float*)d_in[2];
  const float* Wq = (const float*)d_in[3];
  const float* bq = (const float*)d_in[4];
  const float* Wk = (const float*)d_in[5];
  const float* bk = (const float*)d_in[6];
  const float* Wv = (const float*)d_in[7];
  const float* bv = (const float*)d_in[8];
  const float* Wo = (const float*)d_in[9];
  const float* bo = (const float*)d_in[10];

  // per-batch bytes: qb 2.048M + kr 2.048M + vb 2.048M + vt 2.081M + ao 2.048M
  int bc = 8;
  while (bc > 1 && 524288ull + (unsigned long long)bc * 10272768ull > (unsigned long long)ws_size)
    bc >>= 1;

  bf16_t* wt = (bf16_t*)d_ws;                           // 4 * 65536
  bf16_t* qb = wt + 4 * 65536;                          // bc*4000*256
  bf16_t* kr = qb + (size_t)bc * 4000 * 256;            // bc*4000*256
  bf16_t* vb = kr + (size_t)bc * 4000 * 256;            // bc*4000*256
  bf16_t* vt = vb + (size_t)bc * 4000 * 256;            // bc*256*4064
  bf16_t* ao = vt + (size_t)bc * 256 * 4064;            // bc*4000*256

  prep_weights<<<256, 256, 0, stream>>>(Wq, Wk, Wv, Wo, wt);

  const float qscale = 0.07071067811865475f;  // 1/sqrt(200) folded into qb

  for (int b0 = 0; b0 < 8; b0 += bc) {
    const int M = bc * 4000;
    const int mblk = (M + 63) / 64;
    const float* qx = query + (size_t)b0 * 4000 * 256;
    const float* kx = key   + (size_t)b0 * 4000 * 256;
    const float* vx = value + (size_t)b0 * 4000 * 256;
    float* ox = (float*)d_out + (size_t)b0 * 4000 * 256;

    gemmR<1, 0><<<mblk, 256, 0, stream>>>(qx, wt + 0 * 65536, bq, qb, M, qscale);
    gemmR<1, 0><<<mblk, 256, 0, stream>>>(kx, wt + 1 * 65536, bk, kr, M, 1.f);
    gemmR<1, 0><<<mblk, 256, 0, stream>>>(vx, wt + 2 * 65536, bv, vb, M, 1.f);
    vtrans<<<dim3(63, 4, bc), 256, 0, stream>>>(vb, vt);
    attn_win<<<bc * 320, 448, 0, stream>>>(qb, kr, vt, ao);
    gemmR<0, 1><<<mblk, 256, 0, stream>>>(ao, wt + 3 * 65536, bo, ox, M, 1.f);
  }
}